// Round 8
// baseline (90.551 us; speedup 1.0000x reference)
//
#include <hip/hip_runtime.h>

#define T_TOK 32768
#define E_EXP 256
#define K_SEL 8
#define D_DEV 8
#define SLOTS (E_EXP / D_DEV)   // 32 experts per device
#define TOK_PER_BLK 32          // kernel B: tokens per block (256 gather slots)

typedef float floatx4 __attribute__((ext_vector_type(4)));

// ---------------------------------------------------------------------------
// Kernel A: pure streaming zero-fill of out_remap (32 MB). Same pattern as
// the harness fills, which measure 6.3 TB/s on this box.
// ---------------------------------------------------------------------------
__global__ __launch_bounds__(256) void zero_remap_kernel(
    float* __restrict__ out_remap) {
  const size_t i = (size_t)blockIdx.x * 256 + threadIdx.x;
  const floatx4 z4 = {0.f, 0.f, 0.f, 0.f};
  floatx4* o = (floatx4*)out_remap;
#pragma unroll
  for (int r = 0; r < 4; ++r)
    o[i + (size_t)r * (2048u * 256u)] = z4;   // 2048*256*4 = 2M float4 = 32 MB
}

// ---------------------------------------------------------------------------
// Kernel B: gather selected scores and scatter them (4B nt stores, byte-
// masked past L2) into the pre-zeroed remap layout; write reduced_mask.
// Thread tid = (token tl = tid>>3, k = tid&7). 1024 blocks x 256 threads.
// ---------------------------------------------------------------------------
__global__ __launch_bounds__(256) void scatter_kernel(
    const float* __restrict__ topk, const int* __restrict__ mapping,
    const int* __restrict__ meta, float* __restrict__ out_remap,
    float* __restrict__ out_mask) {
  __shared__ int sdev[E_EXP];
  __shared__ int spos[E_EXP];
  __shared__ int scnt[4 * D_DEV];

  const int tid  = threadIdx.x;
  const int w    = tid >> 6;
  const int lane = tid & 63;
  const int tbase = blockIdx.x * TOK_PER_BLK;
  const int tl = tid >> 3;              // this thread's token (0..31)

  // 1) meta (256 consecutive ints, coalesced) then the dependent gather —
  //    address needs only e, so it issues as soon as meta lands; the expert
  //    setup below hides the latency.
  const int e = meta[(size_t)tbase * K_SEL + tid];
  const float sc = topk[(size_t)(tbase + tl) * E_EXP + e];

  // 2) mapping (thread tid = expert tid)
  const int4 m0 = ((const int4*)mapping)[tid * 2];
  const int4 m1 = ((const int4*)mapping)[tid * 2 + 1];

  // 3) expert setup: dev_of_expert (argmax) + stable rank via wave ballots
  {
    int vals[8] = {m0.x, m0.y, m0.z, m0.w, m1.x, m1.y, m1.z, m1.w};
    int best = vals[0], dev = 0;
#pragma unroll
    for (int d = 1; d < 8; ++d)
      if (vals[d] > best) { best = vals[d]; dev = d; }
    sdev[tid] = dev;

    unsigned long long myball = 0ull;
#pragma unroll
    for (int d = 0; d < 8; ++d) {
      unsigned long long b = __ballot(dev == d);
      if (d == dev) myball = b;
      if (lane == d) scnt[w * 8 + d] = __popcll(b);
    }
    const unsigned long long lt = (lane == 0) ? 0ull : (~0ull >> (64 - lane));
    const int lower = __popcll(myball & lt);
    __syncthreads();
    int base = 0;
    for (int d = 0; d < dev; ++d)
      base += scnt[0 * 8 + d] + scnt[1 * 8 + d] + scnt[2 * 8 + d] +
              scnt[3 * 8 + d];
    for (int w2 = 0; w2 < w; ++w2) base += scnt[w2 * 8 + dev];
    spos[tid] = base + lower;
  }
  __syncthreads();   // publish spos/sdev for arbitrary-e reads

  const int pos = spos[e];
  const int dv  = sdev[e];

  // 4) reduced_mask: wave w owns tokens 8w..8w+7 -> 4 rows, via 8 ballots
  {
    unsigned long long bsel = 0ull;
#pragma unroll
    for (int d = 0; d < D_DEV; ++d) {
      unsigned long long b = __ballot(dv == d);
      if ((lane & 7) == d) bsel = b;
    }
    if (lane < 32) {
      const float fm =
          ((bsel >> (16 * (lane >> 3))) & 0xFFFFull) ? 1.0f : 0.0f;
      const int rowi = (tbase >> 1) + (w << 2) + (lane >> 3);
      out_mask[(size_t)rowi * D_DEV + (lane & 7)] = fm;
    }
  }

  // 5) scattered 4B nontemporal store of the selected score
  float* dst = out_remap + (size_t)(pos >> 5) * T_TOK * SLOTS +
               (size_t)(tbase + tl) * SLOTS + (pos & 31);
  __builtin_nontemporal_store(sc, dst);
}

extern "C" void kernel_launch(void* const* d_in, const int* in_sizes, int n_in,
                              void* d_out, int out_size, void* d_ws, size_t ws_size,
                              hipStream_t stream) {
  const float* topk    = (const float*)d_in[0];
  const int*   mapping = (const int*)d_in[1];
  const int*   meta    = (const int*)d_in[2];

  float* out_remap = (float*)d_out;
  float* out_mask  = out_remap + (size_t)D_DEV * T_TOK * SLOTS;  // 8,388,608

  // A: pure-write zero pass (streams at fill speed); B: sparse gather/scatter.
  // Stream order serializes A before B (dispatch-boundary visibility).
  zero_remap_kernel<<<2048, 256, 0, stream>>>(out_remap);
  scatter_kernel<<<T_TOK / TOK_PER_BLK, 256, 0, stream>>>(
      topk, mapping, meta, out_remap, out_mask);
}